// Round 1
// baseline (76.590 us; speedup 1.0000x reference)
//
#include <hip/hip_runtime.h>

// DEC ClusteringLayer: q[i][j] = (1/(1+||x_i - c_j||^2)) / rowsum, ALPHA=1 (exponent == 1).
// ||x-c||^2 = ||x||^2 + ||c||^2 - 2 x.c ; cross term via bf16 MFMA (fp32 MFMA doesn't exist
// on CDNA4), norms + epilogue in fp32. One block = 128 rows x all 256 clusters so the
// row-normalization fuses (no second pass over the 64 MB output).

typedef __attribute__((ext_vector_type(8))) short short8;   // 8 x bf16 fragment (4 VGPRs)
typedef __attribute__((ext_vector_type(4))) float f32x4;    // MFMA 16x16 accumulator

#define BM 128
#define BN 256
#define BK 64
#define DDIM 512
#define NTHREADS 512

__device__ __forceinline__ short f2bf(float f) {
    union { float f; unsigned u; } v; v.f = f;
    unsigned r = v.u + 0x7FFFu + ((v.u >> 16) & 1u);   // RNE
    return (short)(r >> 16);
}

__device__ __forceinline__ short8 pack8(float4 a, float4 b) {
    short8 p;
    p[0] = f2bf(a.x); p[1] = f2bf(a.y); p[2] = f2bf(a.z); p[3] = f2bf(a.w);
    p[4] = f2bf(b.x); p[5] = f2bf(b.y); p[6] = f2bf(b.z); p[7] = f2bf(b.w);
    return p;
}

__device__ __forceinline__ float ssum8(float4 a, float4 b) {
    return a.x*a.x + a.y*a.y + a.z*a.z + a.w*a.w
         + b.x*b.x + b.y*b.y + b.z*b.z + b.w*b.w;
}

// LDS tiles are [row][BK] bf16: row stride = 128 B = exact 32-bank alias on a
// stride-row fragment read -> XOR-swizzle the 16B slot with row&7 (free 2-way after).
__device__ __forceinline__ int lidx(int row, int k) {   // k in shorts, multiple of 8
    return row * BK + (k ^ ((row & 7) << 3));
}

__global__ __launch_bounds__(NTHREADS, 1)
void dec_cluster_kernel(const float* __restrict__ x, const float* __restrict__ cl,
                        float* __restrict__ out) {
    __shared__ __align__(16) short ldsA[BM * BK];   // 16 KB
    __shared__ __align__(16) short ldsB[BN * BK];   // 32 KB
    __shared__ float s_x2[BM];
    __shared__ float s_c2[BN];
    __shared__ float s_rsum[BM];

    const int t    = threadIdx.x;
    const int lane = t & 63;
    const int w    = t >> 6;       // 0..7
    const int rg   = w >> 2;       // 0..1 : row group (64 rows)
    const int cg   = w & 3;        // 0..3 : col group (64 cols)
    const int l15  = lane & 15;
    const int lq   = lane >> 4;
    const int row0 = blockIdx.x * BM;

    f32x4 acc[4][4];
#pragma unroll
    for (int m = 0; m < 4; ++m)
#pragma unroll
        for (int n = 0; n < 4; ++n)
            acc[m][n] = (f32x4){0.f, 0.f, 0.f, 0.f};

    const int srow = t >> 3;           // 0..63  (staging row within 64-row slab)
    const int kseg = (t & 7) << 3;     // 0..56  (8-float segment)

    float x2p0 = 0.f, x2p1 = 0.f;
    float c2p[4] = {0.f, 0.f, 0.f, 0.f};

    for (int k0 = 0; k0 < DDIM; k0 += BK) {
        __syncthreads();
        // ---- stage x tile (128 x 64 fp32 -> bf16), accumulate ||x||^2 partials ----
        {
            const float* g0 = x + (size_t)(row0 + srow) * DDIM + k0 + kseg;
            float4 a0 = *(const float4*)g0;
            float4 a1 = *(const float4*)(g0 + 4);
            x2p0 += ssum8(a0, a1);
            *(short8*)&ldsA[lidx(srow, kseg)] = pack8(a0, a1);

            const float* g1 = x + (size_t)(row0 + srow + 64) * DDIM + k0 + kseg;
            float4 b0 = *(const float4*)g1;
            float4 b1 = *(const float4*)(g1 + 4);
            x2p1 += ssum8(b0, b1);
            *(short8*)&ldsA[lidx(srow + 64, kseg)] = pack8(b0, b1);
        }
        // ---- stage cluster tile (256 x 64), accumulate ||c||^2 partials ----
#pragma unroll
        for (int s = 0; s < 4; ++s) {
            const int crow = srow + (s << 6);
            const float* g = cl + (size_t)crow * DDIM + k0 + kseg;
            float4 a0 = *(const float4*)g;
            float4 a1 = *(const float4*)(g + 4);
            c2p[s] += ssum8(a0, a1);
            *(short8*)&ldsB[lidx(crow, kseg)] = pack8(a0, a1);
        }
        __syncthreads();
        // ---- MFMA: each wave 64x64 = 4x4 fragments, 2 K-steps of 32 ----
#pragma unroll
        for (int kk = 0; kk < BK; kk += 32) {
            const int kf = kk + (lq << 3);
            short8 af[4], bf[4];
#pragma unroll
            for (int m = 0; m < 4; ++m)
                af[m] = *(const short8*)&ldsA[lidx((rg << 6) + (m << 4) + l15, kf)];
#pragma unroll
            for (int n = 0; n < 4; ++n)
                bf[n] = *(const short8*)&ldsB[lidx((cg << 6) + (n << 4) + l15, kf)];
#pragma unroll
            for (int m = 0; m < 4; ++m)
#pragma unroll
                for (int n = 0; n < 4; ++n)
                    acc[m][n] = __builtin_amdgcn_mfma_f32_16x16x32_bf16(
                        af[m], bf[n], acc[m][n], 0, 0, 0);
        }
    }

    // ---- reduce staging-side norm partials (8 threads per row) into LDS ----
    x2p0 += __shfl_xor(x2p0, 1); x2p0 += __shfl_xor(x2p0, 2); x2p0 += __shfl_xor(x2p0, 4);
    x2p1 += __shfl_xor(x2p1, 1); x2p1 += __shfl_xor(x2p1, 2); x2p1 += __shfl_xor(x2p1, 4);
#pragma unroll
    for (int s = 0; s < 4; ++s) {
        c2p[s] += __shfl_xor(c2p[s], 1);
        c2p[s] += __shfl_xor(c2p[s], 2);
        c2p[s] += __shfl_xor(c2p[s], 4);
    }
    if ((t & 7) == 0) {
        s_x2[srow]      = x2p0;
        s_x2[srow + 64] = x2p1;
        s_c2[srow]       = c2p[0];
        s_c2[srow + 64]  = c2p[1];
        s_c2[srow + 128] = c2p[2];
        s_c2[srow + 192] = c2p[3];
    }
    if (t < BM) s_rsum[t] = 0.f;
    __syncthreads();

    // ---- epilogue: d2 -> q_unnorm in-place (C/D layout: col = lane&15, row = (lane>>4)*4+reg) ----
#pragma unroll
    for (int m = 0; m < 4; ++m)
#pragma unroll
        for (int n = 0; n < 4; ++n) {
            const int c = (cg << 6) + (n << 4) + l15;
            const float c2v = s_c2[c];
#pragma unroll
            for (int r = 0; r < 4; ++r) {
                const int rw = (rg << 6) + (m << 4) + (lq << 2) + r;
                float d2 = fmaxf(s_x2[rw] + c2v - 2.0f * acc[m][n][r], 0.0f);
                acc[m][n][r] = 1.0f / (1.0f + d2);   // ALPHA=1 -> exponent 1
            }
        }

    // ---- row sums: per-lane partial over 4 col tiles, 16-lane shuffle, LDS atomic across cg waves
#pragma unroll
    for (int m = 0; m < 4; ++m)
#pragma unroll
        for (int r = 0; r < 4; ++r) {
            float p = acc[m][0][r] + acc[m][1][r] + acc[m][2][r] + acc[m][3][r];
            p += __shfl_xor(p, 1);
            p += __shfl_xor(p, 2);
            p += __shfl_xor(p, 4);
            p += __shfl_xor(p, 8);
            if (l15 == 0) {
                const int rw = (rg << 6) + (m << 4) + (lq << 2) + r;
                atomicAdd(&s_rsum[rw], p);
            }
        }
    __syncthreads();

    // ---- normalize + store ----
#pragma unroll
    for (int m = 0; m < 4; ++m)
#pragma unroll
        for (int r = 0; r < 4; ++r) {
            const int rw = (rg << 6) + (m << 4) + (lq << 2) + r;
            const float rinv = 1.0f / s_rsum[rw];
            float* orow = out + (size_t)(row0 + rw) * BN + (cg << 6) + l15;
#pragma unroll
            for (int n = 0; n < 4; ++n)
                orow[n << 4] = acc[m][n][r] * rinv;
        }
}

extern "C" void kernel_launch(void* const* d_in, const int* in_sizes, int n_in,
                              void* d_out, int out_size, void* d_ws, size_t ws_size,
                              hipStream_t stream) {
    const float* x  = (const float*)d_in[0];
    const float* cl = (const float*)d_in[1];
    float* out = (float*)d_out;
    const int B = in_sizes[0] / DDIM;     // 65536
    dim3 grid(B / BM), block(NTHREADS);
    dec_cluster_kernel<<<grid, block, 0, stream>>>(x, cl, out);
}

// Round 2
// 55.662 us; speedup vs baseline: 1.3760x; 1.3760x over previous
//
#include <hip/hip_runtime.h>

// DEC ClusteringLayer: q[i][j] = (1/(1+||x_i-c_j||^2)) / rowsum, ALPHA=1.
// Cross term via bf16 MFMA. Pipeline: clusters pre-converted to bf16 LDS-image
// layout in ws (one tiny kernel), staged via global_load_lds; x reg-prefetched
// 2 tiles deep; double-buffered LDS with ONE __syncthreads per K-tile so
// prefetch loads stay in flight across the MFMA phase.

typedef __attribute__((ext_vector_type(4))) short short4v;
typedef __attribute__((ext_vector_type(8))) short short8v;
typedef __attribute__((ext_vector_type(4))) float f32x4;

#define DDIM 512
#define KCL  256
#define BM   64
#define BK   32
#define NT   512
#define NTILES 16          // DDIM/BK
#define BTILE  (KCL*BK)    // shorts per B image (8192 = 16 KB)

__device__ __forceinline__ short f2bf(float f) {
    union { float f; unsigned u; } v; v.f = f;
    unsigned r = v.u + 0x7FFFu + ((v.u >> 16) & 1u);   // RNE
    return (short)(r >> 16);
}

__device__ __forceinline__ void glds16(const void* g, void* l) {
    __builtin_amdgcn_global_load_lds(
        (const __attribute__((address_space(1))) unsigned int*)g,
        (__attribute__((address_space(3))) unsigned int*)l, 16, 0, 0);
}

// ---- pre-kernel 1: clusters fp32 -> bf16, fragment-order LDS images in ws ----
// image i (k0=i*32): granule gi in [0,1024): g=gi>>6 (16-row group), lq=(gi>>4)&3,
// l15=gi&15; wsB[(i*1024+gi)*8 + j] = bf16(cl[g*16+l15][i*32 + lq*8 + j]).
// A wave's ds_read_b128 of group g is then base + lane*16: conflict-free.
__global__ void conv_clusters(const float* __restrict__ cl, short* __restrict__ wsB) {
    const int u = blockIdx.x * blockDim.x + threadIdx.x;   // 0..16383
    const int img = u >> 10, gi = u & 1023;
    const int g = gi >> 6, lq = (gi >> 4) & 3, l15 = gi & 15;
    const float* src = cl + (size_t)(g * 16 + l15) * DDIM + img * 32 + lq * 8;
    float4 a = *(const float4*)src;
    float4 b = *(const float4*)(src + 4);
    short8v s;
    s[0]=f2bf(a.x); s[1]=f2bf(a.y); s[2]=f2bf(a.z); s[3]=f2bf(a.w);
    s[4]=f2bf(b.x); s[5]=f2bf(b.y); s[6]=f2bf(b.z); s[7]=f2bf(b.w);
    *(short8v*)&wsB[(size_t)u * 8] = s;
}

// ---- pre-kernel 2: ||c||^2 ----
__global__ void calc_c2(const float* __restrict__ cl, float* __restrict__ c2) {
    const int b = blockIdx.x, l = threadIdx.x;
    const float* src = cl + (size_t)b * DDIM + l * 8;
    float4 a = *(const float4*)src, c = *(const float4*)(src + 4);
    float s = a.x*a.x+a.y*a.y+a.z*a.z+a.w*a.w + c.x*c.x+c.y*c.y+c.z*c.z+c.w*c.w;
    s += __shfl_xor(s,1); s += __shfl_xor(s,2); s += __shfl_xor(s,4);
    s += __shfl_xor(s,8); s += __shfl_xor(s,16); s += __shfl_xor(s,32);
    if (l == 0) c2[b] = s;
}

// ---- main kernel: 64 rows x all 256 clusters per block ----
__global__ __launch_bounds__(NT, 4)
void dec_main(const float* __restrict__ x, const short* __restrict__ wsB,
              const float* __restrict__ wsC2, float* __restrict__ out) {
    __shared__ __align__(16) short lA[2][BM * BK];   // 2 x 4 KB
    __shared__ __align__(16) short lB[2][BTILE];     // 2 x 16 KB
    __shared__ float s_x2[BM];
    __shared__ float s_c2[KCL];
    __shared__ float s_rs[4][BM];

    const int t    = threadIdx.x;
    const int lane = t & 63;
    const int w    = t >> 6;
    const int rg   = w >> 2;          // 0..1 : 32-row group
    const int cg   = w & 3;           // 0..3 : 64-col group
    const int l15  = lane & 15, lq = lane >> 4;
    const int row0 = blockIdx.x * BM;

    // staging geometry: thread t stages x[row0+srow][tile*32 + sk4 .. +3]
    const int srow = t >> 3, sk4 = (t & 7) << 2;
    const float* xbase = x + (size_t)(row0 + srow) * DDIM + sk4;
    const int aidx = (((srow >> 4) * 4 + (sk4 >> 3)) * 16 + (srow & 15)) * 8 + (sk4 & 4);

    if (t < KCL) s_c2[t] = wsC2[t];

    float x2p = 0.f;
    f32x4 acc[2][4];
#pragma unroll
    for (int m = 0; m < 2; ++m)
#pragma unroll
        for (int n = 0; n < 4; ++n) acc[m][n] = (f32x4){0.f, 0.f, 0.f, 0.f};

    auto writeA = [&](short* dst, float4 v) {
        x2p += v.x*v.x + v.y*v.y + v.z*v.z + v.w*v.w;
        short4v s;
        s[0]=f2bf(v.x); s[1]=f2bf(v.y); s[2]=f2bf(v.z); s[3]=f2bf(v.w);
        *(short4v*)&dst[aidx] = s;
    };
    auto gldsB = [&](short* dst, int tile) {
        const short* src = wsB + (size_t)tile * BTILE;
        glds16(src + t * 8, dst + t * 8);                 // round 0: 8 KB
        glds16(src + 4096 + t * 8, dst + 4096 + t * 8);   // round 1: 8 KB
    };
    auto mstep = [&](const short* A, const short* Bt) {
        const short* Ab = A + rg * 1024;
        const short* Bb = Bt + cg * 2048;
        short8v a0 = *(const short8v*)&Ab[lane * 8];
        short8v a1 = *(const short8v*)&Ab[512 + lane * 8];
        short8v b0 = *(const short8v*)&Bb[lane * 8];
        short8v b1 = *(const short8v*)&Bb[512  + lane * 8];
        short8v b2 = *(const short8v*)&Bb[1024 + lane * 8];
        short8v b3 = *(const short8v*)&Bb[1536 + lane * 8];
        acc[0][0] = __builtin_amdgcn_mfma_f32_16x16x32_bf16(a0, b0, acc[0][0], 0,0,0);
        acc[0][1] = __builtin_amdgcn_mfma_f32_16x16x32_bf16(a0, b1, acc[0][1], 0,0,0);
        acc[0][2] = __builtin_amdgcn_mfma_f32_16x16x32_bf16(a0, b2, acc[0][2], 0,0,0);
        acc[0][3] = __builtin_amdgcn_mfma_f32_16x16x32_bf16(a0, b3, acc[0][3], 0,0,0);
        acc[1][0] = __builtin_amdgcn_mfma_f32_16x16x32_bf16(a1, b0, acc[1][0], 0,0,0);
        acc[1][1] = __builtin_amdgcn_mfma_f32_16x16x32_bf16(a1, b1, acc[1][1], 0,0,0);
        acc[1][2] = __builtin_amdgcn_mfma_f32_16x16x32_bf16(a1, b2, acc[1][2], 0,0,0);
        acc[1][3] = __builtin_amdgcn_mfma_f32_16x16x32_bf16(a1, b3, acc[1][3], 0,0,0);
    };

    // prologue: tile0 into buf0 (A via regs, B via gload_lds), x(1) in flight
    float4 xrA = *(const float4*)(xbase);
    gldsB(lB[0], 0);
    float4 xrB = *(const float4*)(xbase + BK);
    writeA(lA[0], xrA);

    for (int tt = 0; tt < NTILES; tt += 2) {
        __syncthreads();                       // buf0 tile tt ready (drains its loads)
        writeA(lA[1], xrB);                    // A(tt+1) -> buf1
        gldsB(lB[1], tt + 1);                  // B(tt+1) -> buf1 (in flight over mfma)
        if (tt < NTILES - 2) xrA = *(const float4*)(xbase + (tt + 2) * BK);
        mstep(lA[0], lB[0]);
        __syncthreads();                       // buf1 tile tt+1 ready
        if (tt < NTILES - 2) { writeA(lA[0], xrA); gldsB(lB[0], tt + 2); }
        if (tt + 3 < NTILES) xrB = *(const float4*)(xbase + (tt + 3) * BK);
        mstep(lA[1], lB[1]);
    }

    // ||x||^2: reduce the 8 k-segment threads per row
    x2p += __shfl_xor(x2p, 1); x2p += __shfl_xor(x2p, 2); x2p += __shfl_xor(x2p, 4);
    if ((t & 7) == 0) s_x2[srow] = x2p;
    __syncthreads();

    // epilogue: d2 -> q_unnorm (C/D: col=l15, row=lq*4+r)
#pragma unroll
    for (int m = 0; m < 2; ++m)
#pragma unroll
        for (int n = 0; n < 4; ++n) {
            const float c2v = s_c2[cg * 64 + n * 16 + l15];
#pragma unroll
            for (int r = 0; r < 4; ++r) {
                const int rw = rg * 32 + m * 16 + lq * 4 + r;
                float d2 = fmaxf(s_x2[rw] + c2v - 2.0f * acc[m][n][r], 0.0f);
                acc[m][n][r] = 1.0f / (1.0f + d2);
            }
        }

    // row sums: 16-lane shuffle, then per-cg slot (deterministic, no atomics)
#pragma unroll
    for (int m = 0; m < 2; ++m)
#pragma unroll
        for (int r = 0; r < 4; ++r) {
            float p = acc[m][0][r] + acc[m][1][r] + acc[m][2][r] + acc[m][3][r];
            p += __shfl_xor(p, 1); p += __shfl_xor(p, 2);
            p += __shfl_xor(p, 4); p += __shfl_xor(p, 8);
            if (l15 == 0) s_rs[cg][rg * 32 + m * 16 + lq * 4 + r] = p;
        }
    __syncthreads();

    // normalize + store
#pragma unroll
    for (int m = 0; m < 2; ++m)
#pragma unroll
        for (int r = 0; r < 4; ++r) {
            const int rw = rg * 32 + m * 16 + lq * 4 + r;
            const float rinv = 1.0f / (s_rs[0][rw] + s_rs[1][rw] + s_rs[2][rw] + s_rs[3][rw]);
            float* o = out + (size_t)(row0 + rw) * KCL + cg * 64 + l15;
#pragma unroll
            for (int n = 0; n < 4; ++n)
                o[n * 16] = acc[m][n][r] * rinv;
        }
}

extern "C" void kernel_launch(void* const* d_in, const int* in_sizes, int n_in,
                              void* d_out, int out_size, void* d_ws, size_t ws_size,
                              hipStream_t stream) {
    const float* x  = (const float*)d_in[0];
    const float* cl = (const float*)d_in[1];
    float* out = (float*)d_out;
    short* wsB  = (short*)d_ws;
    float* wsC2 = (float*)((char*)d_ws + (size_t)NTILES * BTILE * sizeof(short)); // +256 KB

    conv_clusters<<<64, 256, 0, stream>>>(cl, wsB);
    calc_c2<<<KCL, 64, 0, stream>>>(cl, wsC2);
    const int B = in_sizes[0] / DDIM;     // 65536
    dec_main<<<B / BM, NT, 0, stream>>>(x, wsB, wsC2, out);
}